// Round 1
// baseline (265.766 us; speedup 1.0000x reference)
//
#include <hip/hip_runtime.h>
#include <hip/hip_bf16.h>

// Problem: B=16, S=512, N=64, H=768, E_TYPES=9, R_TYPES=10
// Outputs: entity_logits (16*512*9=73728) | entity_repr (16*64*768=786432) |
//          relation_logits (16*2016*10=322560)   — all fp32, concatenated.

#define S_LEN 512
#define H_DIM 768
#define N_ENT 64
#define NPAIR 2016   // 64*63/2

// ---------------------------------------------------------------------------
// Tiled fp32 GEMM: C[M,N] = op(A[M,K] @ B) ; 64x64 tile, BK=16, 4x4 micro.
// MODE 0: B = W1e (K x N row-major, ldb=N), epilogue relu(x + bias[n])
// MODE 1: B = W1r split: col n<768 -> W1r[k*768+n]; n>=768 -> W1r[(k+768)*768+n-768]
//         (ldb=768), plain store.
// M, N multiples of 64; K multiple of 16 (true for all our shapes).
// ---------------------------------------------------------------------------
template<int MODE>
__global__ __launch_bounds__(256) void gemm64_k(
    const float* __restrict__ A, const float* __restrict__ Bsrc,
    const float* __restrict__ bias, float* __restrict__ C,
    int M, int N, int K, int ldb)
{
    __shared__ float As[16][68];   // [k][m], pad 68 -> conflict-light
    __shared__ float Bs[16][64];   // [k][n]

    const int tid = threadIdx.x;
    const int tx = tid & 15, ty = tid >> 4;
    const int m0 = blockIdx.y * 64, n0 = blockIdx.x * 64;

    size_t boff;
    if (MODE == 1) boff = (n0 >= 768) ? ((size_t)768 * 768 + (n0 - 768)) : (size_t)n0;
    else           boff = (size_t)n0;

    const int arow = tid >> 2, akq = tid & 3;   // A: 64 rows x 4 k-quads
    const int bkrow = tid >> 4, bnq = tid & 15; // B: 16 k-rows x 16 n-quads

    const float* Aptr = A + (size_t)(m0 + arow) * K + akq * 4;
    const float* Bptr = Bsrc + boff + (size_t)bkrow * ldb + bnq * 4;

    float acc[4][4] = {};

    for (int k0 = 0; k0 < K; k0 += 16) {
        float4 av = *(const float4*)(Aptr + k0);
        float4 bv = *(const float4*)(Bptr + (size_t)k0 * ldb);
        __syncthreads();
        As[akq * 4 + 0][arow] = av.x;
        As[akq * 4 + 1][arow] = av.y;
        As[akq * 4 + 2][arow] = av.z;
        As[akq * 4 + 3][arow] = av.w;
        *(float4*)&Bs[bkrow][bnq * 4] = bv;
        __syncthreads();
        #pragma unroll
        for (int kk = 0; kk < 16; ++kk) {
            float4 a4 = *(const float4*)&As[kk][ty * 4];
            float4 b4 = *(const float4*)&Bs[kk][tx * 4];
            float ar[4] = {a4.x, a4.y, a4.z, a4.w};
            float br[4] = {b4.x, b4.y, b4.z, b4.w};
            #pragma unroll
            for (int i = 0; i < 4; ++i)
                #pragma unroll
                for (int j = 0; j < 4; ++j)
                    acc[i][j] = fmaf(ar[i], br[j], acc[i][j]);
        }
    }

    #pragma unroll
    for (int i = 0; i < 4; ++i) {
        int row = m0 + ty * 4 + i;
        float* op = C + (size_t)row * N + n0 + tx * 4;
        float4 o;
        if (MODE == 0) {
            float4 bb = *(const float4*)(bias + n0 + tx * 4);
            o.x = fmaxf(acc[i][0] + bb.x, 0.f);
            o.y = fmaxf(acc[i][1] + bb.y, 0.f);
            o.z = fmaxf(acc[i][2] + bb.z, 0.f);
            o.w = fmaxf(acc[i][3] + bb.w, 0.f);
        } else {
            o = make_float4(acc[i][0], acc[i][1], acc[i][2], acc[i][3]);
        }
        *(float4*)op = o;
    }
}

// ---------------------------------------------------------------------------
// K2: entity_logits = H1 (8192x384) @ W2e (384x9) + b2e.  32 rows per block.
// ---------------------------------------------------------------------------
__global__ __launch_bounds__(256) void elog_k(
    const float* __restrict__ H1, const float* __restrict__ W2e,
    const float* __restrict__ b2e, float* __restrict__ out)
{
    __shared__ float Hs[32 * 388];  // rows padded to 388 floats
    __shared__ float Ws[3456];      // 384*9

    const int tid = threadIdx.x;
    const int r0 = blockIdx.x * 32;

    for (int i = tid; i < 32 * 96; i += 256) {
        int row = i / 96, c4 = i % 96;
        float4 h = *(const float4*)(H1 + (size_t)(r0 + row) * 384 + c4 * 4);
        *(float4*)&Hs[row * 388 + c4 * 4] = h;
    }
    for (int i = tid; i < 864; i += 256) {
        *(float4*)&Ws[i * 4] = *(const float4*)(W2e + i * 4);
    }
    __syncthreads();

    for (int o = tid; o < 288; o += 256) {
        int row = o / 9, r = o % 9;
        const float* hp = &Hs[row * 388];
        float acc = 0.f;
        for (int k = 0; k < 384; ++k)
            acc = fmaf(hp[k], Ws[k * 9 + r], acc);
        out[(size_t)(r0 + row) * 9 + r] = acc + b2e[r];
    }
}

// ---------------------------------------------------------------------------
// K3: entity_repr[b,n,:] = mean of seq rows in [start,end) (count>=1)
// ---------------------------------------------------------------------------
__global__ __launch_bounds__(256) void span_k(
    const float* __restrict__ seq, const int* __restrict__ spans,
    float* __restrict__ eout)
{
    const int bn = blockIdx.x;       // 0..1023
    const int b = bn >> 6;
    const int s0 = spans[bn * 2], s1 = spans[bn * 2 + 1];
    int lo = s0 < 0 ? 0 : s0;
    int hi = s1 > S_LEN ? S_LEN : s1;
    int cnt = hi - lo;
    if (cnt < 1) cnt = 1;
    const float inv = 1.f / (float)cnt;
    const int tid = threadIdx.x;

    for (int c = tid; c < H_DIM; c += 256) {
        float acc = 0.f;
        for (int s = lo; s < hi; ++s)
            acc += seq[((size_t)b * S_LEN + s) * H_DIM + c];
        eout[(size_t)bn * H_DIM + c] = acc * inv;
    }
}

// ---------------------------------------------------------------------------
// K5: relation_logits. Per (b, 16x16 pair tile):
//   hidden = relu(U[b,i,:] + V[b,j,:] + b1r); logits = hidden @ W2r + b2r
// UV is (1024 x 1536): cols [0,768) = U, [768,1536) = V.
// ---------------------------------------------------------------------------
__global__ __launch_bounds__(256) void rel_k(
    const float* __restrict__ UV, const float* __restrict__ b1r,
    const float* __restrict__ W2r, const float* __restrict__ b2r,
    float* __restrict__ out)
{
    __shared__ float Ut[16 * 772];   // U rows + b1r, pad stride 772
    __shared__ float Vt[16 * 772];

    const int t = blockIdx.x % 10;   // triu tile id over 4x4 grid of 16-tiles
    const int b = blockIdx.x / 10;
    int it, jt;
    if (t < 4)      { it = 0; jt = t; }
    else if (t < 7) { it = 1; jt = t - 3; }
    else if (t < 9) { it = 2; jt = t - 5; }
    else            { it = 3; jt = 3; }
    const int i0 = it * 16, j0 = jt * 16;
    const int tid = threadIdx.x;

    for (int idx = tid; idx < 16 * 192; idx += 256) {
        int row = idx / 192, c4 = idx % 192;
        float4 u = *(const float4*)(UV + ((size_t)(b * 64 + i0 + row)) * 1536 + c4 * 4);
        float4 bb = *(const float4*)(b1r + c4 * 4);
        u.x += bb.x; u.y += bb.y; u.z += bb.z; u.w += bb.w;
        *(float4*)&Ut[row * 772 + c4 * 4] = u;
        float4 v = *(const float4*)(UV + ((size_t)(b * 64 + j0 + row)) * 1536 + 768 + c4 * 4);
        *(float4*)&Vt[row * 772 + c4 * 4] = v;
    }
    __syncthreads();

    const int ti = tid >> 4, tj = tid & 15;
    const int i = i0 + ti, j = j0 + tj;
    float acc[10] = {};

    #pragma unroll 2
    for (int k4 = 0; k4 < 192; ++k4) {
        float4 u = *(const float4*)&Ut[ti * 772 + k4 * 4];
        float4 v = *(const float4*)&Vt[tj * 772 + k4 * 4];
        const float* wr = W2r + k4 * 40;  // wave-uniform -> scalar loads
        float uu[4] = {u.x, u.y, u.z, u.w};
        float vv[4] = {v.x, v.y, v.z, v.w};
        #pragma unroll
        for (int e = 0; e < 4; ++e) {
            float h = fmaxf(uu[e] + vv[e], 0.f);
            #pragma unroll
            for (int r = 0; r < 10; ++r)
                acc[r] = fmaf(h, wr[e * 10 + r], acc[r]);
        }
    }

    if (j > i) {
        int p = i * 63 - i * (i - 1) / 2 + (j - i - 1);
        float* op = out + ((size_t)(b * NPAIR + p)) * 10;
        #pragma unroll
        for (int r = 0; r < 10; ++r) op[r] = acc[r] + b2r[r];
    }
}

// ---------------------------------------------------------------------------
extern "C" void kernel_launch(void* const* d_in, const int* in_sizes, int n_in,
                              void* d_out, int out_size, void* d_ws, size_t ws_size,
                              hipStream_t stream)
{
    const float* seq   = (const float*)d_in[0];
    // d_in[1] = attention_mask (unused by reference)
    const int*   spans = (const int*)d_in[2];
    const float* W1e   = (const float*)d_in[3];
    const float* b1e   = (const float*)d_in[4];
    const float* W2e   = (const float*)d_in[5];
    const float* b2e   = (const float*)d_in[6];
    const float* W1r   = (const float*)d_in[7];
    const float* b1r   = (const float*)d_in[8];
    const float* W2r   = (const float*)d_in[9];
    const float* b2r   = (const float*)d_in[10];

    float* out  = (float*)d_out;
    float* elog = out;                        // 73728
    float* erep = out + 73728;                // 786432
    float* rlog = out + 73728 + 786432;       // 322560

    float* H1 = (float*)d_ws;                 // 8192*384 fp32 = 12.6 MB
    float* UV = H1 + (size_t)8192 * 384;      // 1024*1536 fp32 = 6.3 MB

    // K1: H1 = relu(seq @ W1e + b1e)   [8192x768 @ 768x384]
    gemm64_k<0><<<dim3(6, 128), 256, 0, stream>>>(seq, W1e, b1e, H1, 8192, 384, 768, 384);
    // K2: entity_logits = H1 @ W2e + b2e
    elog_k<<<256, 256, 0, stream>>>(H1, W2e, b2e, elog);
    // K3: entity_repr
    span_k<<<1024, 256, 0, stream>>>(seq, spans, erep);
    // K4: UV = entity_repr @ [W1r_top | W1r_bot]   [1024x768 @ 768x1536]
    gemm64_k<1><<<dim3(24, 16), 256, 0, stream>>>(erep, W1r, nullptr, UV, 1024, 1536, 768, 768);
    // K5: relation_logits
    rel_k<<<160, 256, 0, stream>>>(UV, b1r, W2r, b2r, rlog);
}

// Round 3
// 209.081 us; speedup vs baseline: 1.2711x; 1.2711x over previous
//
#include <hip/hip_runtime.h>
#include <hip/hip_bf16.h>

// B=16, S=512, N=64, H=768, E_TYPES=9, R_TYPES=10
// out: entity_logits (73728) | entity_repr (786432) | relation_logits (322560), fp32

#define S_LEN 512
#define H_DIM 768
#define NPAIR 2016

typedef __bf16 bf16x8 __attribute__((ext_vector_type(8)));
typedef float f32x4 __attribute__((ext_vector_type(4)));

__device__ __forceinline__ void gload_lds16(const void* g, void* l) {
    __builtin_amdgcn_global_load_lds(
        (const __attribute__((address_space(1))) void*)g,
        (__attribute__((address_space(3))) void*)l, 16, 0, 0);
}

__device__ __forceinline__ ushort f2bf(float x) {
    __hip_bfloat16 h = __float2bfloat16(x);
    return *(ushort*)&h;
}

// ---------------------------------------------------------------------------
// elementwise fp32 -> bf16 cast (float4 in, ushort4 out)
// ---------------------------------------------------------------------------
__global__ __launch_bounds__(256) void cast_k(
    const float* __restrict__ in, ushort* __restrict__ out, int n4)
{
    int i = blockIdx.x * 256 + threadIdx.x;
    const int stride = gridDim.x * 256;
    for (; i < n4; i += stride) {
        float4 v = ((const float4*)in)[i];
        ushort4 o;
        o.x = f2bf(v.x); o.y = f2bf(v.y); o.z = f2bf(v.z); o.w = f2bf(v.w);
        ((ushort4*)out)[i] = o;
    }
}

// ---------------------------------------------------------------------------
// transpose + cast: src[R][C] fp32 -> dst[C][R] bf16 (32x32 LDS tiles)
// ---------------------------------------------------------------------------
__global__ __launch_bounds__(256) void trcast_k(
    const float* __restrict__ src, ushort* __restrict__ dst, int R, int C)
{
    __shared__ float t[32][33];
    const int TR = R >> 5;
    const int br = blockIdx.x % TR, bc = blockIdx.x / TR;
    const int r = threadIdx.x >> 5, c = threadIdx.x & 31;
    #pragma unroll
    for (int p = 0; p < 4; ++p) {
        int rr = r + p * 8;
        t[rr][c] = src[(size_t)(br * 32 + rr) * C + bc * 32 + c];
    }
    __syncthreads();
    #pragma unroll
    for (int p = 0; p < 4; ++p) {
        int rr = r + p * 8;
        dst[(size_t)(bc * 32 + rr) * R + br * 32 + c] = f2bf(t[c][rr]);
    }
}

// ---------------------------------------------------------------------------
// span mean -> entity_repr (fp32 to d_out, bf16 copy to ws for K4)
// ---------------------------------------------------------------------------
__global__ __launch_bounds__(256) void span_k(
    const float* __restrict__ seq, const int* __restrict__ spans,
    float* __restrict__ eout, ushort* __restrict__ ebf)
{
    const int bn = blockIdx.x;       // 0..1023
    const int b = bn >> 6;
    const int s0 = spans[bn * 2], s1 = spans[bn * 2 + 1];
    int lo = s0 < 0 ? 0 : s0;
    int hi = s1 > S_LEN ? S_LEN : s1;
    int cnt = hi - lo;
    if (cnt < 1) cnt = 1;
    const float inv = 1.f / (float)cnt;
    const int tid = threadIdx.x;
    for (int c = tid; c < H_DIM; c += 256) {
        float acc = 0.f;
        for (int s = lo; s < hi; ++s)
            acc += seq[((size_t)b * S_LEN + s) * H_DIM + c];
        float v = acc * inv;
        eout[(size_t)bn * H_DIM + c] = v;
        ebf[(size_t)bn * H_DIM + c] = f2bf(v);
    }
}

// ---------------------------------------------------------------------------
// bf16 MFMA GEMM (m97 structure): C[M,N] = A[M,K] @ Bt[N,K]^T
// 128x128 tile, BK=32, 4 waves (2x2), each wave 64x64 via 4x4 frags 16x16x32.
// EPI 0: bf16 out = relu(acc + bias[n]);  EPI 1: f32 out = acc.
// M,N multiples of 128; K multiple of 32.
// ---------------------------------------------------------------------------
template<int EPI>
__global__ __launch_bounds__(256) void mfma_gemm_k(
    const ushort* __restrict__ A, const ushort* __restrict__ Bt,
    const float* __restrict__ bias, void* __restrict__ Cout,
    int M, int N, int K)
{
    __shared__ ushort As[4096];   // [128 rows][32 k] bf16 = 8KB
    __shared__ ushort Bs[4096];   // [128 cols][32 k] bf16 = 8KB

    const int tid = threadIdx.x;
    const int lane = tid & 63, wid = tid >> 6;
    const int wr = wid >> 1, wc = wid & 1;
    const int m0 = blockIdx.y * 128, n0 = blockIdx.x * 128;
    const int fr = lane & 15, kg = lane >> 4;

    // staging: chunk c (16B = 8 bf16): row=c>>2, kq=c&3. LDS byte = c*16.
    const int srow = tid >> 2, skq = (tid & 3) * 8;
    const ushort* ag0 = A + (size_t)(m0 + srow) * K + skq;
    const ushort* ag1 = A + (size_t)(m0 + 64 + srow) * K + skq;
    const ushort* bg0 = Bt + (size_t)(n0 + srow) * K + skq;
    const ushort* bg1 = Bt + (size_t)(n0 + 64 + srow) * K + skq;
    ushort* al0 = &As[tid * 8];
    ushort* al1 = &As[2048 + tid * 8];
    ushort* bl0 = &Bs[tid * 8];
    ushort* bl1 = &Bs[2048 + tid * 8];

    int aoff[4], boff[4];
    #pragma unroll
    for (int i = 0; i < 4; ++i) {
        aoff[i] = (wr * 64 + i * 16 + fr) * 32 + kg * 8;
        boff[i] = (wc * 64 + i * 16 + fr) * 32 + kg * 8;
    }

    f32x4 acc[4][4] = {};

    for (int k0 = 0; k0 < K; k0 += 32) {
        __syncthreads();                     // prev compute done before overwrite
        gload_lds16(ag0 + k0, al0);
        gload_lds16(ag1 + k0, al1);
        gload_lds16(bg0 + k0, bl0);
        gload_lds16(bg1 + k0, bl1);
        __syncthreads();                     // drains vmcnt before barrier
        bf16x8 af[4], bv[4];
        #pragma unroll
        for (int i = 0; i < 4; ++i) af[i] = *(const bf16x8*)&As[aoff[i]];
        #pragma unroll
        for (int i = 0; i < 4; ++i) bv[i] = *(const bf16x8*)&Bs[boff[i]];
        #pragma unroll
        for (int mi = 0; mi < 4; ++mi)
            #pragma unroll
            for (int nj = 0; nj < 4; ++nj)
                acc[mi][nj] = __builtin_amdgcn_mfma_f32_16x16x32_bf16(
                    af[mi], bv[nj], acc[mi][nj], 0, 0, 0);
    }

    // C/D layout: col = lane&15, row = (lane>>4)*4 + reg  [m89/m91 verified]
    if (EPI == 0) {
        __hip_bfloat16* Cb = (__hip_bfloat16*)Cout;
        float bcol[4];
        #pragma unroll
        for (int nj = 0; nj < 4; ++nj) bcol[nj] = bias[n0 + wc * 64 + nj * 16 + fr];
        #pragma unroll
        for (int mi = 0; mi < 4; ++mi)
            #pragma unroll
            for (int j = 0; j < 4; ++j) {
                size_t rb = (size_t)(m0 + wr * 64 + mi * 16 + kg * 4 + j) * N
                          + n0 + wc * 64 + fr;
                #pragma unroll
                for (int nj = 0; nj < 4; ++nj)
                    Cb[rb + nj * 16] = __float2bfloat16(
                        fmaxf(acc[mi][nj][j] + bcol[nj], 0.f));
            }
    } else {
        float* Cf = (float*)Cout;
        #pragma unroll
        for (int mi = 0; mi < 4; ++mi)
            #pragma unroll
            for (int j = 0; j < 4; ++j) {
                size_t rb = (size_t)(m0 + wr * 64 + mi * 16 + kg * 4 + j) * N
                          + n0 + wc * 64 + fr;
                #pragma unroll
                for (int nj = 0; nj < 4; ++nj)
                    Cf[rb + nj * 16] = acc[mi][nj][j];
            }
    }
}

// ---------------------------------------------------------------------------
// entity_logits = H1bf (8192x384 bf16) @ W2e (384x9) + b2e
// ---------------------------------------------------------------------------
__global__ __launch_bounds__(256) void elog_k(
    const ushort* __restrict__ H1, const float* __restrict__ W2e,
    const float* __restrict__ b2e, float* __restrict__ out)
{
    __shared__ float Hs[32][388];
    __shared__ float Wt[9][384];
    const int tid = threadIdx.x;
    const int r0 = blockIdx.x * 32;

    for (int i = tid; i < 32 * 48; i += 256) {
        int row = i / 48, c8 = i % 48;
        uint4 v = *(const uint4*)(H1 + (size_t)(r0 + row) * 384 + c8 * 8);
        const __hip_bfloat16* hp = (const __hip_bfloat16*)&v;
        #pragma unroll
        for (int e = 0; e < 8; ++e) Hs[row][c8 * 8 + e] = __bfloat162float(hp[e]);
    }
    for (int i = tid; i < 3456; i += 256) {
        int k = i / 9, r = i % 9;
        Wt[r][k] = W2e[i];
    }
    __syncthreads();

    for (int o = tid; o < 288; o += 256) {
        int row = o / 9, r = o % 9;
        float acc = 0.f;
        #pragma unroll 4
        for (int k4 = 0; k4 < 96; ++k4) {
            float4 h = *(const float4*)&Hs[row][k4 * 4];
            float4 w = *(const float4*)&Wt[r][k4 * 4];
            acc = fmaf(h.x, w.x, acc); acc = fmaf(h.y, w.y, acc);
            acc = fmaf(h.z, w.z, acc); acc = fmaf(h.w, w.w, acc);
        }
        out[(size_t)(r0 + row) * 9 + r] = acc + b2e[r];
    }
}

// ---------------------------------------------------------------------------
// relation logits: hidden = relu(U[i]+V[j]+b1r); out = hidden @ W2r + b2r
// ---------------------------------------------------------------------------
__global__ __launch_bounds__(256) void rel_k(
    const float* __restrict__ UV, const float* __restrict__ b1r,
    const float* __restrict__ W2r, const float* __restrict__ b2r,
    float* __restrict__ out)
{
    __shared__ float Ut[16 * 772];
    __shared__ float Vt[16 * 772];

    const int t = blockIdx.x % 10;
    const int b = blockIdx.x / 10;
    int it, jt;
    if (t < 4)      { it = 0; jt = t; }
    else if (t < 7) { it = 1; jt = t - 3; }
    else if (t < 9) { it = 2; jt = t - 5; }
    else            { it = 3; jt = 3; }
    const int i0 = it * 16, j0 = jt * 16;
    const int tid = threadIdx.x;

    for (int idx = tid; idx < 16 * 192; idx += 256) {
        int row = idx / 192, c4 = idx % 192;
        float4 u = *(const float4*)(UV + ((size_t)(b * 64 + i0 + row)) * 1536 + c4 * 4);
        float4 bb = *(const float4*)(b1r + c4 * 4);
        u.x += bb.x; u.y += bb.y; u.z += bb.z; u.w += bb.w;
        *(float4*)&Ut[row * 772 + c4 * 4] = u;
        float4 v = *(const float4*)(UV + ((size_t)(b * 64 + j0 + row)) * 1536 + 768 + c4 * 4);
        *(float4*)&Vt[row * 772 + c4 * 4] = v;
    }
    __syncthreads();

    const int ti = tid >> 4, tj = tid & 15;
    const int i = i0 + ti, j = j0 + tj;
    float acc[10] = {};

    #pragma unroll 2
    for (int k4 = 0; k4 < 192; ++k4) {
        float4 u = *(const float4*)&Ut[ti * 772 + k4 * 4];
        float4 v = *(const float4*)&Vt[tj * 772 + k4 * 4];
        const float* wr = W2r + k4 * 40;
        float uu[4] = {u.x, u.y, u.z, u.w};
        float vv[4] = {v.x, v.y, v.z, v.w};
        #pragma unroll
        for (int e = 0; e < 4; ++e) {
            float h = fmaxf(uu[e] + vv[e], 0.f);
            #pragma unroll
            for (int r = 0; r < 10; ++r)
                acc[r] = fmaf(h, wr[e * 10 + r], acc[r]);
        }
    }

    if (j > i) {
        int p = i * 63 - i * (i - 1) / 2 + (j - i - 1);
        float* op = out + ((size_t)(b * NPAIR + p)) * 10;
        #pragma unroll
        for (int r = 0; r < 10; ++r) op[r] = acc[r] + b2r[r];
    }
}

// ---------------------------------------------------------------------------
extern "C" void kernel_launch(void* const* d_in, const int* in_sizes, int n_in,
                              void* d_out, int out_size, void* d_ws, size_t ws_size,
                              hipStream_t stream)
{
    const float* seq   = (const float*)d_in[0];
    const int*   spans = (const int*)d_in[2];
    const float* W1e   = (const float*)d_in[3];
    const float* b1e   = (const float*)d_in[4];
    const float* W2e   = (const float*)d_in[5];
    const float* b2e   = (const float*)d_in[6];
    const float* W1r   = (const float*)d_in[7];
    const float* b1r   = (const float*)d_in[8];
    const float* W2r   = (const float*)d_in[9];
    const float* b2r   = (const float*)d_in[10];

    float* out  = (float*)d_out;
    float* elog = out;
    float* erep = out + 73728;
    float* rlog = out + 73728 + 786432;

    // ws layout (bytes); UV aliases seq_bf (seq_bf dead after K1, K4 runs later)
    char* ws = (char*)d_ws;
    ushort* seq_bf  = (ushort*)ws;                    // 8192*768*2  = 12,582,912
    float*  UV      = (float*)ws;                     // 1024*1536*4 =  6,291,456 (alias)
    ushort* W1et    = (ushort*)(ws + 12582912);       //  384*768*2  =    589,824
    ushort* W1rt    = (ushort*)(ws + 13172736);       // 1536*768*2  =  2,359,296
    ushort* erep_bf = (ushort*)(ws + 15532032);       // 1024*768*2  =  1,572,864
    ushort* H1bf    = (ushort*)(ws + 17104896);       // 8192*384*2  =  6,291,456
    // total 23,396,352 B

    // casts / transposes
    cast_k<<<2048, 256, 0, stream>>>(seq, seq_bf, (8192 * 768) / 4);
    trcast_k<<<288, 256, 0, stream>>>(W1e, W1et, 768, 384);
    trcast_k<<<576, 256, 0, stream>>>(W1r, W1rt, 768, 768);
    trcast_k<<<576, 256, 0, stream>>>(W1r + 768 * 768, W1rt + 768 * 768, 768, 768);
    // entity_repr (fp32 exact) + bf16 copy
    span_k<<<1024, 256, 0, stream>>>(seq, spans, erep, erep_bf);
    // H1 = relu(seq @ W1e + b1e) -> bf16
    mfma_gemm_k<0><<<dim3(3, 64), 256, 0, stream>>>(seq_bf, W1et, b1e, H1bf, 8192, 384, 768);
    // entity_logits
    elog_k<<<256, 256, 0, stream>>>(H1bf, W2e, b2e, elog);
    // UV = erep @ [W1r_top | W1r_bot]
    mfma_gemm_k<1><<<dim3(12, 8), 256, 0, stream>>>(erep_bf, W1rt, nullptr, UV, 1024, 1536, 768);
    // relation_logits
    rel_k<<<160, 256, 0, stream>>>(UV, b1r, W2r, b2r, rlog);
}